// Round 6
// baseline (229.699 us; speedup 1.0000x reference)
//
#include <hip/hip_runtime.h>
#include <hip/hip_fp16.h>

#define IN_DIM 256
#define OUT_DIM 128
#define SLOPE 0.1f

typedef __attribute__((ext_vector_type(8))) short short8;
typedef __attribute__((ext_vector_type(4))) float f32x4;

// round-to-nearest-even f32 -> bf16 bits
__device__ __forceinline__ unsigned bf16_rne(float f) {
    unsigned u = __float_as_uint(f);
    return (u + 0x7FFFu + ((u >> 16) & 1u)) >> 16;
}

// ---------------------------------------------------------------------------
// K0: pre-split W into bf16 hi/lo once
// ---------------------------------------------------------------------------
__global__ __launch_bounds__(256) void wsplit_kernel(
    const float* __restrict__ W, short* __restrict__ Whi, short* __restrict__ Wlo)
{
    const int i = blockIdx.x * 256 + threadIdx.x;   // 128*256 = 32768 elements
    const float v = W[i];
    const unsigned hb = bf16_rne(v);
    const float hf = __uint_as_float(hb << 16);
    Whi[i] = (short)hb;
    Wlo[i] = (short)bf16_rne(v - hf);
}

// ---------------------------------------------------------------------------
// K1: emb = x @ W^T + b via split-bf16 MFMA (3 terms).
// 64-row M-tile (was 128): grid 1563 = 6.1 blocks/CU, LDS 24 KB (6/CU fit),
// acc 32 VGPR — doubles blocks-in-flight to hide the per-K-step HBM latency
// behind the 2-barrier loop. No embedded atomics (R5 regression: vmcnt
// retires in issue order, so atomic returns gated the x-load waits).
// Fused epilogue: s1 = emb.a1, s2 = emb.a2 (fp32 acc), emb stored fp16.
// ---------------------------------------------------------------------------
__global__ __launch_bounds__(256) void gemm_emb_kernel(
    const float* __restrict__ x, const short* __restrict__ Whi_g,
    const short* __restrict__ Wlo_g, const float* __restrict__ bias,
    const float* __restrict__ a, __half* __restrict__ emb_h,
    float* __restrict__ s1, float* __restrict__ s2, int N)
{
    __shared__ short lds[12288];          // 24 KB
    short* Ahi = lds;                     // 64 x 32 bf16
    short* Alo = lds + 2048;
    short* Bhi = lds + 4096;              // 128 x 32 bf16
    short* Blo = lds + 8192;

    const int tid = threadIdx.x;
    const int l   = tid & 63;
    const int w   = tid >> 6;
    const int gm0 = blockIdx.x * 64;

    // A staging: 64 rows x 4 chunks -> 1 chunk/thread
    const int arow = tid >> 2;            // 0..63
    const int akc  = tid & 3;             // 0..3
    const int gmA  = gm0 + arow;
    const bool av_ok = (gmA < N);
    // B staging: 128 rows x 4 chunks -> 2 chunks/thread
    const int brow = tid >> 1;            // 0..127
    const int bkc0 = (tid & 1) * 2;

    f32x4 acc[8];
    #pragma unroll
    for (int j = 0; j < 8; ++j) acc[j] = (f32x4)0.f;

    float bias_v[8], av1[8], av2[8];
    #pragma unroll
    for (int nf = 0; nf < 8; ++nf) {
        const int col = nf * 16 + (l & 15);
        bias_v[nf] = bias[col];
        av1[nf]    = a[col];
        av2[nf]    = a[OUT_DIM + col];
    }

    for (int ks = 0; ks < 8; ++ks) {
        const int k0 = ks * 32;
        // ---- stage A (f32 -> hi/lo split) ----
        {
            float v[8];
            if (av_ok) {
                const float4 p0 = *(const float4*)&x[(size_t)gmA * IN_DIM + k0 + akc * 8];
                const float4 p1 = *(const float4*)&x[(size_t)gmA * IN_DIM + k0 + akc * 8 + 4];
                v[0]=p0.x; v[1]=p0.y; v[2]=p0.z; v[3]=p0.w;
                v[4]=p1.x; v[5]=p1.y; v[6]=p1.z; v[7]=p1.w;
            } else {
                #pragma unroll
                for (int j = 0; j < 8; ++j) v[j] = 0.f;
            }
            short8 h8, l8;
            #pragma unroll
            for (int j = 0; j < 8; ++j) {
                unsigned hb = bf16_rne(v[j]);
                float hf = __uint_as_float(hb << 16);
                h8[j] = (short)hb;
                l8[j] = (short)bf16_rne(v[j] - hf);
            }
            *(short8*)&Ahi[akc * 512 + arow * 8] = h8;
            *(short8*)&Alo[akc * 512 + arow * 8] = l8;
        }
        // ---- stage B (pure copy of pre-split W) ----
        #pragma unroll
        for (int q = 0; q < 2; ++q) {
            const int kc = bkc0 + q;
            const short8 h8 = *(const short8*)&Whi_g[brow * IN_DIM + k0 + kc * 8];
            const short8 l8 = *(const short8*)&Wlo_g[brow * IN_DIM + k0 + kc * 8];
            *(short8*)&Bhi[kc * 1024 + brow * 8] = h8;
            *(short8*)&Blo[kc * 1024 + brow * 8] = l8;
        }
        __syncthreads();

        // ---- compute: wave w owns rows w*16..w*16+15, all 128 cols ----
        const int arow_f = w * 16 + (l & 15);
        const int aoff   = (l >> 4) * 512 + arow_f * 8;
        const short8 ah = *(const short8*)&Ahi[aoff];
        const short8 al = *(const short8*)&Alo[aoff];
        #pragma unroll
        for (int nf = 0; nf < 8; ++nf) {
            const int col = nf * 16 + (l & 15);
            const int boff = (l >> 4) * 1024 + col * 8;
            const short8 bh = *(const short8*)&Bhi[boff];
            const short8 bl = *(const short8*)&Blo[boff];
            acc[nf] = __builtin_amdgcn_mfma_f32_16x16x32_bf16(ah, bh, acc[nf], 0, 0, 0);
            acc[nf] = __builtin_amdgcn_mfma_f32_16x16x32_bf16(al, bh, acc[nf], 0, 0, 0);
            acc[nf] = __builtin_amdgcn_mfma_f32_16x16x32_bf16(ah, bl, acc[nf], 0, 0, 0);
        }
        __syncthreads();
    }

    // ---- fused epilogue: bias, s1/s2, emb -> fp16 via LDS repack ----
    __half* hl = (__half*)lds;   // [64][144]
    #pragma unroll
    for (int r = 0; r < 4; ++r) {
        const int lrow = w * 16 + (l >> 4) * 4 + r;
        float p1 = 0.f, p2 = 0.f;
        #pragma unroll
        for (int nf = 0; nf < 8; ++nf) {
            const float e = acc[nf][r] + bias_v[nf];
            p1 += e * av1[nf];
            p2 += e * av2[nf];
            hl[lrow * 144 + nf * 16 + (l & 15)] = __float2half(e);
        }
        p1 += __shfl_xor(p1, 1); p1 += __shfl_xor(p1, 2);
        p1 += __shfl_xor(p1, 4); p1 += __shfl_xor(p1, 8);
        p2 += __shfl_xor(p2, 1); p2 += __shfl_xor(p2, 2);
        p2 += __shfl_xor(p2, 4); p2 += __shfl_xor(p2, 8);
        const int gm = gm0 + lrow;
        if ((l & 15) == 0 && gm < N) { s1[gm] = p1; s2[gm] = p2; }
    }
    __syncthreads();
    // coalesced copy LDS fp16 -> global (64 rows x 16 uint4 = 1024 uint4)
    #pragma unroll
    for (int i = 0; i < 4; ++i) {
        const int idx = i * 256 + tid;
        const int row = idx >> 4, seg = idx & 15;
        if (gm0 + row < N) {
            const uint4 u = *(const uint4*)&hl[row * 144 + seg * 8];
            ((uint4*)emb_h)[(size_t)(gm0 + row) * 16 + seg] = u;
        }
    }
}

// ---------------------------------------------------------------------------
// rank: deg counting + per-edge rank, standalone (0 LDS, tiny VGPR -> max
// occupancy), 4 edges/thread = 4 independent atomics in flight.
// ---------------------------------------------------------------------------
__global__ __launch_bounds__(256) void rank_kernel(
    const int* __restrict__ edges, int* __restrict__ deg,
    int* __restrict__ rank, int E)
{
    const int e0 = (blockIdx.x * 256 + threadIdx.x) * 4;
    if (e0 + 3 < E) {
        const int4 ea = ((const int4*)edges)[(e0 >> 1) + 0];
        const int4 eb = ((const int4*)edges)[(e0 >> 1) + 1];
        const int r0 = atomicAdd(&deg[ea.x], 1);
        const int r1 = atomicAdd(&deg[ea.z], 1);
        const int r2 = atomicAdd(&deg[eb.x], 1);
        const int r3 = atomicAdd(&deg[eb.z], 1);
        ((int4*)rank)[e0 >> 2] = make_int4(r0, r1, r2, r3);
    } else if (e0 < E) {
        for (int e = e0; e < E; ++e) {
            const int2 ed = ((const int2*)edges)[e];
            rank[e] = atomicAdd(&deg[ed.x], 1);
        }
    }
}

__global__ __launch_bounds__(256) void scan1_kernel(
    const int* __restrict__ deg, int* __restrict__ off,
    int* __restrict__ bsum, int N)
{
    __shared__ int lds[256];
    const int t = threadIdx.x;
    const int base = blockIdx.x * 1024 + t * 4;
    int v[4];
    int ts = 0;
    #pragma unroll
    for (int j = 0; j < 4; ++j) {
        v[j] = (base + j < N) ? deg[base + j] : 0;
        ts += v[j];
    }
    lds[t] = ts;
    __syncthreads();
    for (int d = 1; d < 256; d <<= 1) {
        int xv = (t >= d) ? lds[t - d] : 0;
        __syncthreads();
        lds[t] += xv;
        __syncthreads();
    }
    int run = lds[t] - ts;
    #pragma unroll
    for (int j = 0; j < 4; ++j) {
        if (base + j < N) off[base + j] = run;
        run += v[j];
    }
    if (t == 255) bsum[blockIdx.x] = lds[255];
}

__global__ __launch_bounds__(256) void scan2_kernel(int* __restrict__ bsum, int nb)
{
    __shared__ int lds[256];
    const int t = threadIdx.x;
    const int v = (t < nb) ? bsum[t] : 0;
    lds[t] = v;
    __syncthreads();
    for (int d = 1; d < 256; d <<= 1) {
        int xv = (t >= d) ? lds[t - d] : 0;
        __syncthreads();
        lds[t] += xv;
        __syncthreads();
    }
    if (t < nb) bsum[t] = lds[t] - v;
}

// scan3: finalize offsets + detect bidx==arange (flag stays 0 if identity)
__global__ __launch_bounds__(256) void scan3_kernel(
    int* __restrict__ off, const int* __restrict__ bsum,
    const int* __restrict__ bidx, int* __restrict__ flag, int N, int E)
{
    const int i = blockIdx.x * 256 + threadIdx.x;
    if (i < N) {
        off[i] += bsum[i >> 10];
        if (bidx[i] != i) atomicOr(flag, 1);
    }
    if (i == 0) off[N] = E;
}

// ---------------------------------------------------------------------------
// fill: no atomic — pos = precomputed rank. 4 edges/thread for ILP.
// ---------------------------------------------------------------------------
__global__ __launch_bounds__(256) void fill_kernel(
    const int* __restrict__ edges, const int* __restrict__ off,
    const int* __restrict__ rank, int* __restrict__ csr, int E)
{
    const int e0 = (blockIdx.x * 256 + threadIdx.x) * 4;
    if (e0 + 3 < E) {
        const int4 ea = ((const int4*)edges)[(e0 >> 1) + 0];
        const int4 eb = ((const int4*)edges)[(e0 >> 1) + 1];
        const int4 rk = ((const int4*)rank)[e0 >> 2];
        csr[off[ea.x] + rk.x] = ea.y;
        csr[off[ea.z] + rk.y] = ea.w;
        csr[off[eb.x] + rk.z] = eb.y;
        csr[off[eb.z] + rk.w] = eb.w;
    } else if (e0 < E) {
        for (int e = e0; e < E; ++e) {
            const int2 ed = ((const int2*)edges)[e];
            csr[off[ed.x] + rank[e]] = ed.y;
        }
    }
}

// ---------------------------------------------------------------------------
// K3: gather aggregation. Wave = 4 edge-groups x 16 col-lanes, 16 edges per
// iteration in 4 batched phases (4 independent gathers in flight per lane).
// ---------------------------------------------------------------------------
__global__ __launch_bounds__(256) void agg_kernel(
    const int* __restrict__ off, const int* __restrict__ csr,
    const float* __restrict__ s1, const float* __restrict__ s2,
    const __half* __restrict__ emb_h, const int* __restrict__ flag,
    float* __restrict__ results, float* __restrict__ out, int N)
{
    const int wid  = (int)((blockIdx.x * 256u + threadIdx.x) >> 6);
    const int lane = threadIdx.x & 63;
    if (wid >= N) return;
    const int eg = lane >> 4;
    const int cl = lane & 15;
    const int beg = off[wid];
    const int end = off[wid + 1];
    const float s1n = s1[wid];

    const float4* __restrict__ embrow = (const float4*)emb_h;

    float av[8];
    #pragma unroll
    for (int k = 0; k < 8; ++k) av[k] = 0.f;
    float rs = 0.f;

    for (int base = beg; base < end; base += 16) {
        int dq[4];
        #pragma unroll
        for (int q = 0; q < 4; ++q) {
            const int idx = base + q * 4 + eg;
            dq[q] = (idx < end) ? csr[idx] : -1;
        }
        float scq[4];
        #pragma unroll
        for (int q = 0; q < 4; ++q) {
            if (dq[q] >= 0) {
                const float ll = s1n + s2[dq[q]];
                scq[q] = __expf(ll > 0.f ? ll : SLOPE * ll);
            } else {
                scq[q] = 0.f;
                dq[q]  = 0;
            }
        }
        float4 vq[4];
        #pragma unroll
        for (int q = 0; q < 4; ++q)
            vq[q] = embrow[(size_t)dq[q] * 16 + cl];
        #pragma unroll
        for (int q = 0; q < 4; ++q) {
            rs += scq[q];
            const __half2* hp = reinterpret_cast<const __half2*>(&vq[q]);
            #pragma unroll
            for (int k = 0; k < 4; ++k) {
                const float2 f = __half22float2(hp[k]);
                av[2 * k]     += scq[q] * f.x;
                av[2 * k + 1] += scq[q] * f.y;
            }
        }
    }

    #pragma unroll
    for (int k = 0; k < 8; ++k) {
        av[k] += __shfl_xor(av[k], 16);
        av[k] += __shfl_xor(av[k], 32);
    }
    rs += __shfl_xor(rs, 16);
    rs += __shfl_xor(rs, 32);

    const float inv = 1.f / (rs > 0.f ? rs : 1.f);
    if (eg == 0) {
        float* dbuf = (*flag == 0) ? out : results;
        float4* rp = (float4*)&dbuf[(size_t)wid * 128 + cl * 8];
        rp[0] = make_float4(av[0] * inv, av[1] * inv, av[2] * inv, av[3] * inv);
        rp[1] = make_float4(av[4] * inv, av[5] * inv, av[6] * inv, av[7] * inv);
    }
}

// ---------------------------------------------------------------------------
// K4: out[i] = results[batch_idx[i]] — skipped when identity (agg wrote out)
// ---------------------------------------------------------------------------
__global__ __launch_bounds__(256) void gather_kernel(
    const float* __restrict__ results, const int* __restrict__ bidx,
    const int* __restrict__ flag, float* __restrict__ out, int N)
{
    if (*flag == 0) return;
    const unsigned i = blockIdx.x * 256u + threadIdx.x;
    if (i >= (unsigned)N * 32u) return;
    const unsigned n = i >> 5, c = i & 31;
    ((float4*)out)[i] = ((const float4*)results)[(size_t)bidx[n] * 32 + c];
}

extern "C" void kernel_launch(void* const* d_in, const int* in_sizes, int n_in,
                              void* d_out, int out_size, void* d_ws, size_t ws_size,
                              hipStream_t stream) {
    const float* x     = (const float*)d_in[0];
    const float* W     = (const float*)d_in[1];
    const float* b     = (const float*)d_in[2];
    const float* a     = (const float*)d_in[3];
    const int*   edges = (const int*)d_in[4];
    const int*   bidx  = (const int*)d_in[5];

    const int N = in_sizes[5];
    const int E = in_sizes[4] / 2;

    // workspace (big 16B-aligned arrays first; rank/csr aligned for int4)
    float*  results = (float*)d_ws;                          // N*128 f
    __half* emb_h   = (__half*)(results + (size_t)N * OUT_DIM); // N*128 h
    int*    rank    = (int*)(emb_h + (size_t)N * OUT_DIM);   // E
    int*    csr     = rank + E;                              // E
    float*  s1      = (float*)(csr + E);                     // N
    float*  s2      = s1 + N;                                // N
    int*    deg     = (int*)(s2 + N);                        // N
    int*    flag    = deg + N;                               // 1
    int*    off     = flag + 1;                              // N+1
    int*    bsum    = off + N + 1;                           // 256
    short*  Whi     = (short*)(bsum + 256);
    short*  Wlo     = Whi + OUT_DIM * IN_DIM;

    // zero deg[N] and flag together
    hipMemsetAsync(deg, 0, (size_t)(N + 1) * sizeof(int), stream);

    wsplit_kernel<<<(OUT_DIM * IN_DIM) / 256, 256, 0, stream>>>(W, Whi, Wlo);

    dim3 gGemm((N + 63) / 64);
    gemm_emb_kernel<<<gGemm, 256, 0, stream>>>(x, Whi, Wlo, b, a, emb_h, s1, s2, N);

    const int gE4 = (E / 4 + 255) / 256 + 1;
    rank_kernel<<<gE4, 256, 0, stream>>>(edges, deg, rank, E);

    const int nb = (N + 1023) / 1024;
    scan1_kernel<<<nb, 256, 0, stream>>>(deg, off, bsum, N);
    scan2_kernel<<<1, 256, 0, stream>>>(bsum, nb);
    scan3_kernel<<<(N + 255) / 256, 256, 0, stream>>>(off, bsum, bidx, flag, N, E);

    fill_kernel<<<gE4, 256, 0, stream>>>(edges, off, rank, csr, E);

    const unsigned aggThreads = (unsigned)N * 64u;
    agg_kernel<<<(aggThreads + 255u) / 256u, 256, 0, stream>>>(
        off, csr, s1, s2, emb_h, flag, results, (float*)d_out, N);

    const unsigned gatherThreads = (unsigned)N * 32u;
    gather_kernel<<<(gatherThreads + 255u) / 256u, 256, 0, stream>>>(
        results, bidx, flag, (float*)d_out, N);
}

// Round 7
// 228.227 us; speedup vs baseline: 1.0065x; 1.0065x over previous
//
#include <hip/hip_runtime.h>
#include <hip/hip_fp16.h>

#define IN_DIM 256
#define OUT_DIM 128
#define SLOPE 0.1f

typedef __attribute__((ext_vector_type(8))) short short8;
typedef __attribute__((ext_vector_type(4))) float f32x4;

// round-to-nearest-even f32 -> bf16 bits
__device__ __forceinline__ unsigned bf16_rne(float f) {
    unsigned u = __float_as_uint(f);
    return (u + 0x7FFFu + ((u >> 16) & 1u)) >> 16;
}

// ---------------------------------------------------------------------------
// K0: pre-split W into bf16 hi/lo once
// ---------------------------------------------------------------------------
__global__ __launch_bounds__(256) void wsplit_kernel(
    const float* __restrict__ W, short* __restrict__ Whi, short* __restrict__ Wlo)
{
    const int i = blockIdx.x * 256 + threadIdx.x;   // 128*256 = 32768 elements
    const float v = W[i];
    const unsigned hb = bf16_rne(v);
    const float hf = __uint_as_float(hb << 16);
    Whi[i] = (short)hb;
    Wlo[i] = (short)bf16_rne(v - hf);
}

// ---------------------------------------------------------------------------
// K1: emb = x @ W^T + b via split-bf16 MFMA (3 terms).
// 64-row M-tile: grid 1563 = 6.1 blocks/CU, LDS 24 KB, acc 32 VGPR.
// Fused epilogue: s1 = emb.a1, s2 = emb.a2 (fp32 acc), emb stored fp16.
// ---------------------------------------------------------------------------
__global__ __launch_bounds__(256) void gemm_emb_kernel(
    const float* __restrict__ x, const short* __restrict__ Whi_g,
    const short* __restrict__ Wlo_g, const float* __restrict__ bias,
    const float* __restrict__ a, __half* __restrict__ emb_h,
    float* __restrict__ s1, float* __restrict__ s2, int N)
{
    __shared__ short lds[12288];          // 24 KB
    short* Ahi = lds;                     // 64 x 32 bf16
    short* Alo = lds + 2048;
    short* Bhi = lds + 4096;              // 128 x 32 bf16
    short* Blo = lds + 8192;

    const int tid = threadIdx.x;
    const int l   = tid & 63;
    const int w   = tid >> 6;
    const int gm0 = blockIdx.x * 64;

    // A staging: 64 rows x 4 chunks -> 1 chunk/thread
    const int arow = tid >> 2;            // 0..63
    const int akc  = tid & 3;             // 0..3
    const int gmA  = gm0 + arow;
    const bool av_ok = (gmA < N);
    // B staging: 128 rows x 4 chunks -> 2 chunks/thread
    const int brow = tid >> 1;            // 0..127
    const int bkc0 = (tid & 1) * 2;

    f32x4 acc[8];
    #pragma unroll
    for (int j = 0; j < 8; ++j) acc[j] = (f32x4)0.f;

    float bias_v[8], av1[8], av2[8];
    #pragma unroll
    for (int nf = 0; nf < 8; ++nf) {
        const int col = nf * 16 + (l & 15);
        bias_v[nf] = bias[col];
        av1[nf]    = a[col];
        av2[nf]    = a[OUT_DIM + col];
    }

    for (int ks = 0; ks < 8; ++ks) {
        const int k0 = ks * 32;
        // ---- stage A (f32 -> hi/lo split) ----
        {
            float v[8];
            if (av_ok) {
                const float4 p0 = *(const float4*)&x[(size_t)gmA * IN_DIM + k0 + akc * 8];
                const float4 p1 = *(const float4*)&x[(size_t)gmA * IN_DIM + k0 + akc * 8 + 4];
                v[0]=p0.x; v[1]=p0.y; v[2]=p0.z; v[3]=p0.w;
                v[4]=p1.x; v[5]=p1.y; v[6]=p1.z; v[7]=p1.w;
            } else {
                #pragma unroll
                for (int j = 0; j < 8; ++j) v[j] = 0.f;
            }
            short8 h8, l8;
            #pragma unroll
            for (int j = 0; j < 8; ++j) {
                unsigned hb = bf16_rne(v[j]);
                float hf = __uint_as_float(hb << 16);
                h8[j] = (short)hb;
                l8[j] = (short)bf16_rne(v[j] - hf);
            }
            *(short8*)&Ahi[akc * 512 + arow * 8] = h8;
            *(short8*)&Alo[akc * 512 + arow * 8] = l8;
        }
        // ---- stage B (pure copy of pre-split W) ----
        #pragma unroll
        for (int q = 0; q < 2; ++q) {
            const int kc = bkc0 + q;
            const short8 h8 = *(const short8*)&Whi_g[brow * IN_DIM + k0 + kc * 8];
            const short8 l8 = *(const short8*)&Wlo_g[brow * IN_DIM + k0 + kc * 8];
            *(short8*)&Bhi[kc * 1024 + brow * 8] = h8;
            *(short8*)&Blo[kc * 1024 + brow * 8] = l8;
        }
        __syncthreads();

        // ---- compute: wave w owns rows w*16..w*16+15, all 128 cols ----
        const int arow_f = w * 16 + (l & 15);
        const int aoff   = (l >> 4) * 512 + arow_f * 8;
        const short8 ah = *(const short8*)&Ahi[aoff];
        const short8 al = *(const short8*)&Alo[aoff];
        #pragma unroll
        for (int nf = 0; nf < 8; ++nf) {
            const int col = nf * 16 + (l & 15);
            const int boff = (l >> 4) * 1024 + col * 8;
            const short8 bh = *(const short8*)&Bhi[boff];
            const short8 bl = *(const short8*)&Blo[boff];
            acc[nf] = __builtin_amdgcn_mfma_f32_16x16x32_bf16(ah, bh, acc[nf], 0, 0, 0);
            acc[nf] = __builtin_amdgcn_mfma_f32_16x16x32_bf16(al, bh, acc[nf], 0, 0, 0);
            acc[nf] = __builtin_amdgcn_mfma_f32_16x16x32_bf16(ah, bl, acc[nf], 0, 0, 0);
        }
        __syncthreads();
    }

    // ---- fused epilogue: bias, s1/s2, emb -> fp16 via LDS repack ----
    __half* hl = (__half*)lds;   // [64][144]
    #pragma unroll
    for (int r = 0; r < 4; ++r) {
        const int lrow = w * 16 + (l >> 4) * 4 + r;
        float p1 = 0.f, p2 = 0.f;
        #pragma unroll
        for (int nf = 0; nf < 8; ++nf) {
            const float e = acc[nf][r] + bias_v[nf];
            p1 += e * av1[nf];
            p2 += e * av2[nf];
            hl[lrow * 144 + nf * 16 + (l & 15)] = __float2half(e);
        }
        p1 += __shfl_xor(p1, 1); p1 += __shfl_xor(p1, 2);
        p1 += __shfl_xor(p1, 4); p1 += __shfl_xor(p1, 8);
        p2 += __shfl_xor(p2, 1); p2 += __shfl_xor(p2, 2);
        p2 += __shfl_xor(p2, 4); p2 += __shfl_xor(p2, 8);
        const int gm = gm0 + lrow;
        if ((l & 15) == 0 && gm < N) { s1[gm] = p1; s2[gm] = p2; }
    }
    __syncthreads();
    // coalesced copy LDS fp16 -> global (64 rows x 16 uint4 = 1024 uint4)
    #pragma unroll
    for (int i = 0; i < 4; ++i) {
        const int idx = i * 256 + tid;
        const int row = idx >> 4, seg = idx & 15;
        if (gm0 + row < N) {
            const uint4 u = *(const uint4*)&hl[row * 144 + seg * 8];
            ((uint4*)emb_h)[(size_t)(gm0 + row) * 16 + seg] = u;
        }
    }
}

// ---------------------------------------------------------------------------
// rank: deg counting + per-edge rank, standalone (0 LDS, tiny VGPR -> max
// occupancy), 4 edges/thread = 4 independent atomics in flight.
// ---------------------------------------------------------------------------
__global__ __launch_bounds__(256) void rank_kernel(
    const int* __restrict__ edges, int* __restrict__ deg,
    int* __restrict__ rank, int E)
{
    const int e0 = (blockIdx.x * 256 + threadIdx.x) * 4;
    if (e0 + 3 < E) {
        const int4 ea = ((const int4*)edges)[(e0 >> 1) + 0];
        const int4 eb = ((const int4*)edges)[(e0 >> 1) + 1];
        const int r0 = atomicAdd(&deg[ea.x], 1);
        const int r1 = atomicAdd(&deg[ea.z], 1);
        const int r2 = atomicAdd(&deg[eb.x], 1);
        const int r3 = atomicAdd(&deg[eb.z], 1);
        ((int4*)rank)[e0 >> 2] = make_int4(r0, r1, r2, r3);
    } else if (e0 < E) {
        for (int e = e0; e < E; ++e) {
            const int2 ed = ((const int2*)edges)[e];
            rank[e] = atomicAdd(&deg[ed.x], 1);
        }
    }
}

__global__ __launch_bounds__(256) void scan1_kernel(
    const int* __restrict__ deg, int* __restrict__ off,
    int* __restrict__ bsum, int N)
{
    __shared__ int lds[256];
    const int t = threadIdx.x;
    const int base = blockIdx.x * 1024 + t * 4;
    int v[4];
    int ts = 0;
    #pragma unroll
    for (int j = 0; j < 4; ++j) {
        v[j] = (base + j < N) ? deg[base + j] : 0;
        ts += v[j];
    }
    lds[t] = ts;
    __syncthreads();
    for (int d = 1; d < 256; d <<= 1) {
        int xv = (t >= d) ? lds[t - d] : 0;
        __syncthreads();
        lds[t] += xv;
        __syncthreads();
    }
    int run = lds[t] - ts;
    #pragma unroll
    for (int j = 0; j < 4; ++j) {
        if (base + j < N) off[base + j] = run;
        run += v[j];
    }
    if (t == 255) bsum[blockIdx.x] = lds[255];
}

__global__ __launch_bounds__(256) void scan2_kernel(int* __restrict__ bsum, int nb)
{
    __shared__ int lds[256];
    const int t = threadIdx.x;
    const int v = (t < nb) ? bsum[t] : 0;
    lds[t] = v;
    __syncthreads();
    for (int d = 1; d < 256; d <<= 1) {
        int xv = (t >= d) ? lds[t - d] : 0;
        __syncthreads();
        lds[t] += xv;
        __syncthreads();
    }
    if (t < nb) bsum[t] = lds[t] - v;
}

// scan3: finalize offsets + detect bidx==arange (flag stays 0 if identity)
__global__ __launch_bounds__(256) void scan3_kernel(
    int* __restrict__ off, const int* __restrict__ bsum,
    const int* __restrict__ bidx, int* __restrict__ flag, int N, int E)
{
    const int i = blockIdx.x * 256 + threadIdx.x;
    if (i < N) {
        off[i] += bsum[i >> 10];
        if (bidx[i] != i) atomicOr(flag, 1);
    }
    if (i == 0) off[N] = E;
}

// ---------------------------------------------------------------------------
// fill: no atomic — pos = precomputed rank. 4 edges/thread for ILP.
// ---------------------------------------------------------------------------
__global__ __launch_bounds__(256) void fill_kernel(
    const int* __restrict__ edges, const int* __restrict__ off,
    const int* __restrict__ rank, int* __restrict__ csr, int E)
{
    const int e0 = (blockIdx.x * 256 + threadIdx.x) * 4;
    if (e0 + 3 < E) {
        const int4 ea = ((const int4*)edges)[(e0 >> 1) + 0];
        const int4 eb = ((const int4*)edges)[(e0 >> 1) + 1];
        const int4 rk = ((const int4*)rank)[e0 >> 2];
        csr[off[ea.x] + rk.x] = ea.y;
        csr[off[ea.z] + rk.y] = ea.w;
        csr[off[eb.x] + rk.z] = eb.y;
        csr[off[eb.z] + rk.w] = eb.w;
    } else if (e0 < E) {
        for (int e = e0; e < E; ++e) {
            const int2 ed = ((const int2*)edges)[e];
            csr[off[ed.x] + rank[e]] = ed.y;
        }
    }
}

// ---------------------------------------------------------------------------
// K3: gather aggregation. Wave = 4 edge-groups x 16 col-lanes.
// Main loop: UNGUARDED 16-edge iterations (no per-edge compares, no dummy
// loads). Tail: one iteration executing only ceil(rem/4) phases — the skip
// is wave-uniform (beg/end uniform per wave) so dead phases cost a branch.
// Unpack+accumulate written as sc * __half2float(h) so the compiler can fuse
// cvt+fma into v_fma_mix_f32 (halves inner-loop VALU).
// ---------------------------------------------------------------------------
__global__ __launch_bounds__(256) void agg_kernel(
    const int* __restrict__ off, const int* __restrict__ csr,
    const float* __restrict__ s1, const float* __restrict__ s2,
    const __half* __restrict__ emb_h, const int* __restrict__ flag,
    float* __restrict__ results, float* __restrict__ out, int N)
{
    const int wid  = (int)((blockIdx.x * 256u + threadIdx.x) >> 6);
    const int lane = threadIdx.x & 63;
    if (wid >= N) return;
    const int eg = lane >> 4;
    const int cl = lane & 15;
    const int beg = off[wid];
    const int end = off[wid + 1];
    const float s1n = s1[wid];

    const float4* __restrict__ embrow = (const float4*)emb_h;

    float av[8];
    #pragma unroll
    for (int k = 0; k < 8; ++k) av[k] = 0.f;
    float rs = 0.f;

    int base = beg;
    // ---- main loop: full 16-edge iterations, zero guards ----
    for (; base + 16 <= end; base += 16) {
        int dq[4];
        #pragma unroll
        for (int q = 0; q < 4; ++q)
            dq[q] = csr[base + q * 4 + eg];
        float scq[4];
        #pragma unroll
        for (int q = 0; q < 4; ++q) {
            const float ll = s1n + s2[dq[q]];
            scq[q] = __expf(ll > 0.f ? ll : SLOPE * ll);
        }
        float4 vq[4];
        #pragma unroll
        for (int q = 0; q < 4; ++q)
            vq[q] = embrow[(size_t)dq[q] * 16 + cl];
        #pragma unroll
        for (int q = 0; q < 4; ++q) {
            rs += scq[q];
            const __half* hp = reinterpret_cast<const __half*>(&vq[q]);
            #pragma unroll
            for (int k = 0; k < 8; ++k)
                av[k] += scq[q] * __half2float(hp[k]);
        }
    }
    // ---- tail: only ceil(rem/4) phases run (uniform skip) ----
    if (base < end) {
        const int nq = ((end - base) + 3) >> 2;   // 1..4, wave-uniform
        int dq[4];
        float scq[4];
        #pragma unroll
        for (int q = 0; q < 4; ++q) {
            dq[q] = 0; scq[q] = 0.f;
            if (q < nq) {
                const int idx = base + q * 4 + eg;
                if (idx < end) {
                    dq[q] = csr[idx];
                    const float ll = s1n + s2[dq[q]];
                    scq[q] = __expf(ll > 0.f ? ll : SLOPE * ll);
                }
            }
        }
        float4 vq[4];
        #pragma unroll
        for (int q = 0; q < 4; ++q)
            if (q < nq) vq[q] = embrow[(size_t)dq[q] * 16 + cl];
        #pragma unroll
        for (int q = 0; q < 4; ++q) {
            if (q < nq) {
                rs += scq[q];
                const __half* hp = reinterpret_cast<const __half*>(&vq[q]);
                #pragma unroll
                for (int k = 0; k < 8; ++k)
                    av[k] += scq[q] * __half2float(hp[k]);
            }
        }
    }

    #pragma unroll
    for (int k = 0; k < 8; ++k) {
        av[k] += __shfl_xor(av[k], 16);
        av[k] += __shfl_xor(av[k], 32);
    }
    rs += __shfl_xor(rs, 16);
    rs += __shfl_xor(rs, 32);

    const float inv = 1.f / (rs > 0.f ? rs : 1.f);
    if (eg == 0) {
        float* dbuf = (*flag == 0) ? out : results;
        float4* rp = (float4*)&dbuf[(size_t)wid * 128 + cl * 8];
        rp[0] = make_float4(av[0] * inv, av[1] * inv, av[2] * inv, av[3] * inv);
        rp[1] = make_float4(av[4] * inv, av[5] * inv, av[6] * inv, av[7] * inv);
    }
}

// ---------------------------------------------------------------------------
// K4: out[i] = results[batch_idx[i]] — skipped when identity (agg wrote out)
// ---------------------------------------------------------------------------
__global__ __launch_bounds__(256) void gather_kernel(
    const float* __restrict__ results, const int* __restrict__ bidx,
    const int* __restrict__ flag, float* __restrict__ out, int N)
{
    if (*flag == 0) return;
    const unsigned i = blockIdx.x * 256u + threadIdx.x;
    if (i >= (unsigned)N * 32u) return;
    const unsigned n = i >> 5, c = i & 31;
    ((float4*)out)[i] = ((const float4*)results)[(size_t)bidx[n] * 32 + c];
}

extern "C" void kernel_launch(void* const* d_in, const int* in_sizes, int n_in,
                              void* d_out, int out_size, void* d_ws, size_t ws_size,
                              hipStream_t stream) {
    const float* x     = (const float*)d_in[0];
    const float* W     = (const float*)d_in[1];
    const float* b     = (const float*)d_in[2];
    const float* a     = (const float*)d_in[3];
    const int*   edges = (const int*)d_in[4];
    const int*   bidx  = (const int*)d_in[5];

    const int N = in_sizes[5];
    const int E = in_sizes[4] / 2;

    // workspace (big 16B-aligned arrays first; rank/csr aligned for int4)
    float*  results = (float*)d_ws;                          // N*128 f
    __half* emb_h   = (__half*)(results + (size_t)N * OUT_DIM); // N*128 h
    int*    rank    = (int*)(emb_h + (size_t)N * OUT_DIM);   // E
    int*    csr     = rank + E;                              // E
    float*  s1      = (float*)(csr + E);                     // N
    float*  s2      = s1 + N;                                // N
    int*    deg     = (int*)(s2 + N);                        // N
    int*    flag    = deg + N;                               // 1
    int*    off     = flag + 1;                              // N+1
    int*    bsum    = off + N + 1;                           // 256
    short*  Whi     = (short*)(bsum + 256);
    short*  Wlo     = Whi + OUT_DIM * IN_DIM;

    // zero deg[N] and flag together
    hipMemsetAsync(deg, 0, (size_t)(N + 1) * sizeof(int), stream);

    wsplit_kernel<<<(OUT_DIM * IN_DIM) / 256, 256, 0, stream>>>(W, Whi, Wlo);

    dim3 gGemm((N + 63) / 64);
    gemm_emb_kernel<<<gGemm, 256, 0, stream>>>(x, Whi, Wlo, b, a, emb_h, s1, s2, N);

    const int gE4 = (E / 4 + 255) / 256 + 1;
    rank_kernel<<<gE4, 256, 0, stream>>>(edges, deg, rank, E);

    const int nb = (N + 1023) / 1024;
    scan1_kernel<<<nb, 256, 0, stream>>>(deg, off, bsum, N);
    scan2_kernel<<<1, 256, 0, stream>>>(bsum, nb);
    scan3_kernel<<<(N + 255) / 256, 256, 0, stream>>>(off, bsum, bidx, flag, N, E);

    fill_kernel<<<gE4, 256, 0, stream>>>(edges, off, rank, csr, E);

    const unsigned aggThreads = (unsigned)N * 64u;
    agg_kernel<<<(aggThreads + 255u) / 256u, 256, 0, stream>>>(
        off, csr, s1, s2, emb_h, flag, results, (float*)d_out, N);

    const unsigned gatherThreads = (unsigned)N * 32u;
    gather_kernel<<<(gatherThreads + 255u) / 256u, 256, 0, stream>>>(
        results, bidx, flag, (float*)d_out, N);
}

// Round 8
// 225.080 us; speedup vs baseline: 1.0205x; 1.0140x over previous
//
#include <hip/hip_runtime.h>
#include <hip/hip_fp16.h>

#define IN_DIM 256
#define OUT_DIM 128
#define SLOPE 0.1f

typedef __attribute__((ext_vector_type(8))) short short8;
typedef __attribute__((ext_vector_type(4))) float f32x4;

// round-to-nearest-even f32 -> bf16 bits
__device__ __forceinline__ unsigned bf16_rne(float f) {
    unsigned u = __float_as_uint(f);
    return (u + 0x7FFFu + ((u >> 16) & 1u)) >> 16;
}

// ---------------------------------------------------------------------------
// K0: pre-split W into bf16 hi/lo once
// ---------------------------------------------------------------------------
__global__ __launch_bounds__(256) void wsplit_kernel(
    const float* __restrict__ W, short* __restrict__ Whi, short* __restrict__ Wlo)
{
    const int i = blockIdx.x * 256 + threadIdx.x;   // 128*256 = 32768 elements
    const float v = W[i];
    const unsigned hb = bf16_rne(v);
    const float hf = __uint_as_float(hb << 16);
    Whi[i] = (short)hb;
    Wlo[i] = (short)bf16_rne(v - hf);
}

// ---------------------------------------------------------------------------
// K1: emb = x @ W^T + b via split-bf16 MFMA (3 terms).
// 64-row M-tile: grid 1563 = 6.1 blocks/CU, LDS 24 KB, acc 32 VGPR.
// Fused epilogue: s1 = emb.a1, s2 = emb.a2 (fp32 acc), emb stored fp16.
// ---------------------------------------------------------------------------
__global__ __launch_bounds__(256) void gemm_emb_kernel(
    const float* __restrict__ x, const short* __restrict__ Whi_g,
    const short* __restrict__ Wlo_g, const float* __restrict__ bias,
    const float* __restrict__ a, __half* __restrict__ emb_h,
    float* __restrict__ s1, float* __restrict__ s2, int N)
{
    __shared__ short lds[12288];          // 24 KB
    short* Ahi = lds;                     // 64 x 32 bf16
    short* Alo = lds + 2048;
    short* Bhi = lds + 4096;              // 128 x 32 bf16
    short* Blo = lds + 8192;

    const int tid = threadIdx.x;
    const int l   = tid & 63;
    const int w   = tid >> 6;
    const int gm0 = blockIdx.x * 64;

    // A staging: 64 rows x 4 chunks -> 1 chunk/thread
    const int arow = tid >> 2;            // 0..63
    const int akc  = tid & 3;             // 0..3
    const int gmA  = gm0 + arow;
    const bool av_ok = (gmA < N);
    // B staging: 128 rows x 4 chunks -> 2 chunks/thread
    const int brow = tid >> 1;            // 0..127
    const int bkc0 = (tid & 1) * 2;

    f32x4 acc[8];
    #pragma unroll
    for (int j = 0; j < 8; ++j) acc[j] = (f32x4)0.f;

    float bias_v[8], av1[8], av2[8];
    #pragma unroll
    for (int nf = 0; nf < 8; ++nf) {
        const int col = nf * 16 + (l & 15);
        bias_v[nf] = bias[col];
        av1[nf]    = a[col];
        av2[nf]    = a[OUT_DIM + col];
    }

    for (int ks = 0; ks < 8; ++ks) {
        const int k0 = ks * 32;
        // ---- stage A (f32 -> hi/lo split) ----
        {
            float v[8];
            if (av_ok) {
                const float4 p0 = *(const float4*)&x[(size_t)gmA * IN_DIM + k0 + akc * 8];
                const float4 p1 = *(const float4*)&x[(size_t)gmA * IN_DIM + k0 + akc * 8 + 4];
                v[0]=p0.x; v[1]=p0.y; v[2]=p0.z; v[3]=p0.w;
                v[4]=p1.x; v[5]=p1.y; v[6]=p1.z; v[7]=p1.w;
            } else {
                #pragma unroll
                for (int j = 0; j < 8; ++j) v[j] = 0.f;
            }
            short8 h8, l8;
            #pragma unroll
            for (int j = 0; j < 8; ++j) {
                unsigned hb = bf16_rne(v[j]);
                float hf = __uint_as_float(hb << 16);
                h8[j] = (short)hb;
                l8[j] = (short)bf16_rne(v[j] - hf);
            }
            *(short8*)&Ahi[akc * 512 + arow * 8] = h8;
            *(short8*)&Alo[akc * 512 + arow * 8] = l8;
        }
        // ---- stage B (pure copy of pre-split W) ----
        #pragma unroll
        for (int q = 0; q < 2; ++q) {
            const int kc = bkc0 + q;
            const short8 h8 = *(const short8*)&Whi_g[brow * IN_DIM + k0 + kc * 8];
            const short8 l8 = *(const short8*)&Wlo_g[brow * IN_DIM + k0 + kc * 8];
            *(short8*)&Bhi[kc * 1024 + brow * 8] = h8;
            *(short8*)&Blo[kc * 1024 + brow * 8] = l8;
        }
        __syncthreads();

        // ---- compute: wave w owns rows w*16..w*16+15, all 128 cols ----
        const int arow_f = w * 16 + (l & 15);
        const int aoff   = (l >> 4) * 512 + arow_f * 8;
        const short8 ah = *(const short8*)&Ahi[aoff];
        const short8 al = *(const short8*)&Alo[aoff];
        #pragma unroll
        for (int nf = 0; nf < 8; ++nf) {
            const int col = nf * 16 + (l & 15);
            const int boff = (l >> 4) * 1024 + col * 8;
            const short8 bh = *(const short8*)&Bhi[boff];
            const short8 bl = *(const short8*)&Blo[boff];
            acc[nf] = __builtin_amdgcn_mfma_f32_16x16x32_bf16(ah, bh, acc[nf], 0, 0, 0);
            acc[nf] = __builtin_amdgcn_mfma_f32_16x16x32_bf16(al, bh, acc[nf], 0, 0, 0);
            acc[nf] = __builtin_amdgcn_mfma_f32_16x16x32_bf16(ah, bl, acc[nf], 0, 0, 0);
        }
        __syncthreads();
    }

    // ---- fused epilogue: bias, s1/s2, emb -> fp16 via LDS repack ----
    __half* hl = (__half*)lds;   // [64][144]
    #pragma unroll
    for (int r = 0; r < 4; ++r) {
        const int lrow = w * 16 + (l >> 4) * 4 + r;
        float p1 = 0.f, p2 = 0.f;
        #pragma unroll
        for (int nf = 0; nf < 8; ++nf) {
            const float e = acc[nf][r] + bias_v[nf];
            p1 += e * av1[nf];
            p2 += e * av2[nf];
            hl[lrow * 144 + nf * 16 + (l & 15)] = __float2half(e);
        }
        p1 += __shfl_xor(p1, 1); p1 += __shfl_xor(p1, 2);
        p1 += __shfl_xor(p1, 4); p1 += __shfl_xor(p1, 8);
        p2 += __shfl_xor(p2, 1); p2 += __shfl_xor(p2, 2);
        p2 += __shfl_xor(p2, 4); p2 += __shfl_xor(p2, 8);
        const int gm = gm0 + lrow;
        if ((l & 15) == 0 && gm < N) { s1[gm] = p1; s2[gm] = p2; }
    }
    __syncthreads();
    // coalesced copy LDS fp16 -> global (64 rows x 16 uint4 = 1024 uint4)
    #pragma unroll
    for (int i = 0; i < 4; ++i) {
        const int idx = i * 256 + tid;
        const int row = idx >> 4, seg = idx & 15;
        if (gm0 + row < N) {
            const uint4 u = *(const uint4*)&hl[row * 144 + seg * 8];
            ((uint4*)emb_h)[(size_t)(gm0 + row) * 16 + seg] = u;
        }
    }
}

// ---------------------------------------------------------------------------
// rank: deg counting + per-edge rank, standalone (0 LDS, tiny VGPR -> max
// occupancy), 4 edges/thread = 4 independent atomics in flight.
// ---------------------------------------------------------------------------
__global__ __launch_bounds__(256) void rank_kernel(
    const int* __restrict__ edges, int* __restrict__ deg,
    int* __restrict__ rank, int E)
{
    const int e0 = (blockIdx.x * 256 + threadIdx.x) * 4;
    if (e0 + 3 < E) {
        const int4 ea = ((const int4*)edges)[(e0 >> 1) + 0];
        const int4 eb = ((const int4*)edges)[(e0 >> 1) + 1];
        const int r0 = atomicAdd(&deg[ea.x], 1);
        const int r1 = atomicAdd(&deg[ea.z], 1);
        const int r2 = atomicAdd(&deg[eb.x], 1);
        const int r3 = atomicAdd(&deg[eb.z], 1);
        ((int4*)rank)[e0 >> 2] = make_int4(r0, r1, r2, r3);
    } else if (e0 < E) {
        for (int e = e0; e < E; ++e) {
            const int2 ed = ((const int2*)edges)[e];
            rank[e] = atomicAdd(&deg[ed.x], 1);
        }
    }
}

__global__ __launch_bounds__(256) void scan1_kernel(
    const int* __restrict__ deg, int* __restrict__ off,
    int* __restrict__ bsum, int N)
{
    __shared__ int lds[256];
    const int t = threadIdx.x;
    const int base = blockIdx.x * 1024 + t * 4;
    int v[4];
    int ts = 0;
    #pragma unroll
    for (int j = 0; j < 4; ++j) {
        v[j] = (base + j < N) ? deg[base + j] : 0;
        ts += v[j];
    }
    lds[t] = ts;
    __syncthreads();
    for (int d = 1; d < 256; d <<= 1) {
        int xv = (t >= d) ? lds[t - d] : 0;
        __syncthreads();
        lds[t] += xv;
        __syncthreads();
    }
    int run = lds[t] - ts;
    #pragma unroll
    for (int j = 0; j < 4; ++j) {
        if (base + j < N) off[base + j] = run;
        run += v[j];
    }
    if (t == 255) bsum[blockIdx.x] = lds[255];
}

// scan3 (scan2 fused): each block computes its own bsum prefix (<=256 adds),
// finalizes offsets, detects bidx==arange (flag stays 0 if identity).
__global__ __launch_bounds__(256) void scan3_kernel(
    int* __restrict__ off, const int* __restrict__ bsum,
    const int* __restrict__ bidx, int* __restrict__ flag, int N, int E)
{
    __shared__ int red[256];
    const int t = threadIdx.x;
    const int chunk = (int)(blockIdx.x >> 2);   // block's 1024-chunk (uniform)
    int s = 0;
    for (int j = t; j < chunk; j += 256) s += bsum[j];
    red[t] = s;
    __syncthreads();
    #pragma unroll
    for (int d = 128; d > 0; d >>= 1) {
        if (t < d) red[t] += red[t + d];
        __syncthreads();
    }
    const int pref = red[0];
    const int i = blockIdx.x * 256 + t;
    if (i < N) {
        off[i] += pref;
        if (bidx[i] != i) atomicOr(flag, 1);
    }
    if (i == 0) off[N] = E;
}

// ---------------------------------------------------------------------------
// fill: no atomic — pos = precomputed rank. 4 edges/thread for ILP.
// ---------------------------------------------------------------------------
__global__ __launch_bounds__(256) void fill_kernel(
    const int* __restrict__ edges, const int* __restrict__ off,
    const int* __restrict__ rank, int* __restrict__ csr, int E)
{
    const int e0 = (blockIdx.x * 256 + threadIdx.x) * 4;
    if (e0 + 3 < E) {
        const int4 ea = ((const int4*)edges)[(e0 >> 1) + 0];
        const int4 eb = ((const int4*)edges)[(e0 >> 1) + 1];
        const int4 rk = ((const int4*)rank)[e0 >> 2];
        csr[off[ea.x] + rk.x] = ea.y;
        csr[off[ea.z] + rk.y] = ea.w;
        csr[off[eb.x] + rk.z] = eb.y;
        csr[off[eb.z] + rk.w] = eb.w;
    } else if (e0 < E) {
        for (int e = e0; e < E; ++e) {
            const int2 ed = ((const int2*)edges)[e];
            csr[off[ed.x] + rank[e]] = ed.y;
        }
    }
}

// ---------------------------------------------------------------------------
// K3: gather aggregation. Wave = 1 node.
// Phase 1 (lane-parallel, per 64-edge tile): each lane computes the score of
// ONE edge (coalesced csr, 1 s2 gather, 1 exp — was 16x redundant per group)
// and stashes (dst,score) in wave-private LDS. Row-sum accumulates here.
// Phase 2: 4 groups x 16 col-lanes read pairs back via broadcast ds_read,
// 32 edges per iter (up to 8 row-gathers in flight per lane).
// Wave-synchronous LDS (per-wave slots, uniform bounds) — no __syncthreads.
// ---------------------------------------------------------------------------
__global__ __launch_bounds__(256) void agg_kernel(
    const int* __restrict__ off, const int* __restrict__ csr,
    const float* __restrict__ s1, const float* __restrict__ s2,
    const __half* __restrict__ emb_h, const int* __restrict__ flag,
    float* __restrict__ results, float* __restrict__ out, int N)
{
    __shared__ int2 sl[4][64];   // [wave][slot] = {dst, score bits}  (2 KB)

    const int wid  = (int)((blockIdx.x * 256u + threadIdx.x) >> 6);
    const int lane = threadIdx.x & 63;
    const int wv   = threadIdx.x >> 6;
    if (wid >= N) return;
    const int eg = lane >> 4;
    const int cl = lane & 15;
    const int beg = off[wid];
    const int end = off[wid + 1];
    const float s1n = s1[wid];

    const float4* __restrict__ embrow = (const float4*)emb_h;
    int2* slot = &sl[wv][0];

    float av[8];
    #pragma unroll
    for (int k = 0; k < 8; ++k) av[k] = 0.f;
    float rsl = 0.f;

    for (int tile = beg; tile < end; tile += 64) {
        const int cnt = min(64, end - tile);           // wave-uniform
        // ---- phase 1: one edge per lane ----
        int d = 0; float sc = 0.f;
        if (lane < cnt) {
            d = csr[tile + lane];
            const float ll = s1n + s2[d];
            sc = __expf(ll > 0.f ? ll : SLOPE * ll);
        }
        rsl += sc;
        slot[lane] = make_int2(d, __float_as_int(sc));
        __builtin_amdgcn_wave_barrier();
        // ---- phase 2: grouped gather, 32 edges / iter ----
        for (int j0 = 0; j0 < cnt; j0 += 32) {
            const int nq = ((cnt - j0) + 3) >> 2;      // 1..8, wave-uniform
            int dq[8]; float scq[8];
            #pragma unroll
            for (int q = 0; q < 8; ++q) {
                dq[q] = 0; scq[q] = 0.f;
                if (q < nq) {
                    const int2 p = slot[j0 + q * 4 + eg];
                    dq[q] = p.x; scq[q] = __int_as_float(p.y);
                }
            }
            float4 vq[8];
            #pragma unroll
            for (int q = 0; q < 8; ++q)
                if (q < nq) vq[q] = embrow[(size_t)dq[q] * 16 + cl];
            #pragma unroll
            for (int q = 0; q < 8; ++q) {
                if (q < nq) {
                    const __half* hp = reinterpret_cast<const __half*>(&vq[q]);
                    #pragma unroll
                    for (int k = 0; k < 8; ++k)
                        av[k] += scq[q] * __half2float(hp[k]);
                }
            }
        }
        __builtin_amdgcn_wave_barrier();   // before next tile reuses slots
    }

    // row-sum: full 64-lane reduce of per-lane partials
    float rs = rsl;
    rs += __shfl_xor(rs, 1);  rs += __shfl_xor(rs, 2);
    rs += __shfl_xor(rs, 4);  rs += __shfl_xor(rs, 8);
    rs += __shfl_xor(rs, 16); rs += __shfl_xor(rs, 32);
    // av: reduce across the 4 edge-groups (lane bits 4,5)
    #pragma unroll
    for (int k = 0; k < 8; ++k) {
        av[k] += __shfl_xor(av[k], 16);
        av[k] += __shfl_xor(av[k], 32);
    }

    const float inv = 1.f / (rs > 0.f ? rs : 1.f);
    if (eg == 0) {
        float* dbuf = (*flag == 0) ? out : results;
        float4* rp = (float4*)&dbuf[(size_t)wid * 128 + cl * 8];
        rp[0] = make_float4(av[0] * inv, av[1] * inv, av[2] * inv, av[3] * inv);
        rp[1] = make_float4(av[4] * inv, av[5] * inv, av[6] * inv, av[7] * inv);
    }
}

// ---------------------------------------------------------------------------
// K4: out[i] = results[batch_idx[i]] — skipped when identity (agg wrote out)
// ---------------------------------------------------------------------------
__global__ __launch_bounds__(256) void gather_kernel(
    const float* __restrict__ results, const int* __restrict__ bidx,
    const int* __restrict__ flag, float* __restrict__ out, int N)
{
    if (*flag == 0) return;
    const unsigned i = blockIdx.x * 256u + threadIdx.x;
    if (i >= (unsigned)N * 32u) return;
    const unsigned n = i >> 5, c = i & 31;
    ((float4*)out)[i] = ((const float4*)results)[(size_t)bidx[n] * 32 + c];
}

extern "C" void kernel_launch(void* const* d_in, const int* in_sizes, int n_in,
                              void* d_out, int out_size, void* d_ws, size_t ws_size,
                              hipStream_t stream) {
    const float* x     = (const float*)d_in[0];
    const float* W     = (const float*)d_in[1];
    const float* b     = (const float*)d_in[2];
    const float* a     = (const float*)d_in[3];
    const int*   edges = (const int*)d_in[4];
    const int*   bidx  = (const int*)d_in[5];

    const int N = in_sizes[5];
    const int E = in_sizes[4] / 2;

    // workspace (big 16B-aligned arrays first; rank/csr aligned for int4)
    float*  results = (float*)d_ws;                          // N*128 f
    __half* emb_h   = (__half*)(results + (size_t)N * OUT_DIM); // N*128 h
    int*    rank    = (int*)(emb_h + (size_t)N * OUT_DIM);   // E
    int*    csr     = rank + E;                              // E
    float*  s1      = (float*)(csr + E);                     // N
    float*  s2      = s1 + N;                                // N
    int*    deg     = (int*)(s2 + N);                        // N
    int*    flag    = deg + N;                               // 1
    int*    off     = flag + 1;                              // N+1
    int*    bsum    = off + N + 1;                           // 256
    short*  Whi     = (short*)(bsum + 256);
    short*  Wlo     = Whi + OUT_DIM * IN_DIM;

    // zero deg[N] and flag together
    hipMemsetAsync(deg, 0, (size_t)(N + 1) * sizeof(int), stream);

    wsplit_kernel<<<(OUT_DIM * IN_DIM) / 256, 256, 0, stream>>>(W, Whi, Wlo);

    dim3 gGemm((N + 63) / 64);
    gemm_emb_kernel<<<gGemm, 256, 0, stream>>>(x, Whi, Wlo, b, a, emb_h, s1, s2, N);

    const int gE4 = (E / 4 + 255) / 256 + 1;
    rank_kernel<<<gE4, 256, 0, stream>>>(edges, deg, rank, E);

    const int nb = (N + 1023) / 1024;
    scan1_kernel<<<nb, 256, 0, stream>>>(deg, off, bsum, N);
    scan3_kernel<<<(N + 255) / 256, 256, 0, stream>>>(off, bsum, bidx, flag, N, E);

    fill_kernel<<<gE4, 256, 0, stream>>>(edges, off, rank, csr, E);

    const unsigned aggThreads = (unsigned)N * 64u;
    agg_kernel<<<(aggThreads + 255u) / 256u, 256, 0, stream>>>(
        off, csr, s1, s2, emb_h, flag, results, (float*)d_out, N);

    const unsigned gatherThreads = (unsigned)N * 32u;
    gather_kernel<<<(gatherThreads + 255u) / 256u, 256, 0, stream>>>(
        results, bidx, flag, (float*)d_out, N);
}

// Round 9
// 213.363 us; speedup vs baseline: 1.0766x; 1.0549x over previous
//
#include <hip/hip_runtime.h>
#include <hip/hip_fp16.h>

#define IN_DIM 256
#define OUT_DIM 128
#define SLOPE 0.1f

typedef __attribute__((ext_vector_type(8))) short short8;
typedef __attribute__((ext_vector_type(4))) float f32x4;

// round-to-nearest-even f32 -> bf16 bits
__device__ __forceinline__ unsigned bf16_rne(float f) {
    unsigned u = __float_as_uint(f);
    return (u + 0x7FFFu + ((u >> 16) & 1u)) >> 16;
}

// ---------------------------------------------------------------------------
// K0: pre-split W into bf16 hi/lo once
// ---------------------------------------------------------------------------
__global__ __launch_bounds__(256) void wsplit_kernel(
    const float* __restrict__ W, short* __restrict__ Whi, short* __restrict__ Wlo)
{
    const int i = blockIdx.x * 256 + threadIdx.x;   // 128*256 = 32768 elements
    const float v = W[i];
    const unsigned hb = bf16_rne(v);
    const float hf = __uint_as_float(hb << 16);
    Whi[i] = (short)hb;
    Wlo[i] = (short)bf16_rne(v - hf);
}

// ---------------------------------------------------------------------------
// K1: emb = x @ W^T + b via split-bf16 MFMA (3 terms), 64-row M-tile.
// Fused TRICKLED rank pass: ONE atomic per thread per K-iteration, issued at
// the top of the compute phase (after staging loads are consumed), with the
// edge src pre-loaded one iteration ahead. Each atomic gets the ds_read+MFMA
// phase to complete before the next barrier's vmcnt drain — no burst queue
// (R5's failure), no separate-block serialization (R3's failure). The ~72us
// memory-side atomic wall overlaps the ~45us of MFMA work.
// Fused epilogue: s1 = emb.a1, s2 = emb.a2 (fp32 acc), emb fp16, rank[] out.
// ---------------------------------------------------------------------------
__global__ __launch_bounds__(256) void gemm_emb_kernel(
    const float* __restrict__ x, const short* __restrict__ Whi_g,
    const short* __restrict__ Wlo_g, const float* __restrict__ bias,
    const float* __restrict__ a, __half* __restrict__ emb_h,
    float* __restrict__ s1, float* __restrict__ s2,
    const int* __restrict__ edges, int* __restrict__ deg,
    int* __restrict__ rank, int N, int E, int ept)
{
    __shared__ short lds[12288];          // 24 KB
    short* Ahi = lds;                     // 64 x 32 bf16
    short* Alo = lds + 2048;
    short* Bhi = lds + 4096;              // 128 x 32 bf16
    short* Blo = lds + 8192;

    const int tid = threadIdx.x;
    const int l   = tid & 63;
    const int w   = tid >> 6;
    const int gm0 = blockIdx.x * 64;

    // rank work assignment (coalesced: e = gtid + ks*T)
    const int gtid = blockIdx.x * 256 + tid;
    const int T    = (int)gridDim.x * 256;
    int rnk[8];
    #pragma unroll
    for (int i = 0; i < 8; ++i) rnk[i] = 0;

    // A staging: 64 rows x 4 chunks -> 1 chunk/thread
    const int arow = tid >> 2;            // 0..63
    const int akc  = tid & 3;             // 0..3
    const int gmA  = gm0 + arow;
    const bool av_ok = (gmA < N);
    // B staging: 128 rows x 4 chunks -> 2 chunks/thread
    const int brow = tid >> 1;            // 0..127
    const int bkc0 = (tid & 1) * 2;

    f32x4 acc[8];
    #pragma unroll
    for (int j = 0; j < 8; ++j) acc[j] = (f32x4)0.f;

    float bias_v[8], av1[8], av2[8];
    #pragma unroll
    for (int nf = 0; nf < 8; ++nf) {
        const int col = nf * 16 + (l & 15);
        bias_v[nf] = bias[col];
        av1[nf]    = a[col];
        av2[nf]    = a[OUT_DIM + col];
    }

    // pre-load src of edge for ks=0 (completes under first staging drain)
    int src_cur = 0;
    if (0 < ept && gtid < E) src_cur = edges[2 * (size_t)gtid];

    #pragma unroll
    for (int ks = 0; ks < 8; ++ks) {
        const int k0 = ks * 32;
        // ---- stage A (f32 -> hi/lo split) ----
        {
            float v[8];
            if (av_ok) {
                const float4 p0 = *(const float4*)&x[(size_t)gmA * IN_DIM + k0 + akc * 8];
                const float4 p1 = *(const float4*)&x[(size_t)gmA * IN_DIM + k0 + akc * 8 + 4];
                v[0]=p0.x; v[1]=p0.y; v[2]=p0.z; v[3]=p0.w;
                v[4]=p1.x; v[5]=p1.y; v[6]=p1.z; v[7]=p1.w;
            } else {
                #pragma unroll
                for (int j = 0; j < 8; ++j) v[j] = 0.f;
            }
            short8 h8, l8;
            #pragma unroll
            for (int j = 0; j < 8; ++j) {
                unsigned hb = bf16_rne(v[j]);
                float hf = __uint_as_float(hb << 16);
                h8[j] = (short)hb;
                l8[j] = (short)bf16_rne(v[j] - hf);
            }
            *(short8*)&Ahi[akc * 512 + arow * 8] = h8;
            *(short8*)&Alo[akc * 512 + arow * 8] = l8;
        }
        // ---- stage B (pure copy of pre-split W) ----
        #pragma unroll
        for (int q = 0; q < 2; ++q) {
            const int kc = bkc0 + q;
            const short8 h8 = *(const short8*)&Whi_g[brow * IN_DIM + k0 + kc * 8];
            const short8 l8 = *(const short8*)&Wlo_g[brow * IN_DIM + k0 + kc * 8];
            *(short8*)&Bhi[kc * 1024 + brow * 8] = h8;
            *(short8*)&Blo[kc * 1024 + brow * 8] = l8;
        }
        __syncthreads();

        // ---- trickled rank work (compute-phase window) ----
        int src_nxt = 0;
        if (ks + 1 < ept) {
            const int en = gtid + (ks + 1) * T;
            if (en < E) src_nxt = edges[2 * (size_t)en];
        }
        if (ks < ept) {
            const int e = gtid + ks * T;
            if (e < E) rnk[ks] = atomicAdd(&deg[src_cur], 1);
        }
        src_cur = src_nxt;

        // ---- compute: wave w owns rows w*16..w*16+15, all 128 cols ----
        const int arow_f = w * 16 + (l & 15);
        const int aoff   = (l >> 4) * 512 + arow_f * 8;
        const short8 ah = *(const short8*)&Ahi[aoff];
        const short8 al = *(const short8*)&Alo[aoff];
        #pragma unroll
        for (int nf = 0; nf < 8; ++nf) {
            const int col = nf * 16 + (l & 15);
            const int boff = (l >> 4) * 1024 + col * 8;
            const short8 bh = *(const short8*)&Bhi[boff];
            const short8 bl = *(const short8*)&Blo[boff];
            acc[nf] = __builtin_amdgcn_mfma_f32_16x16x32_bf16(ah, bh, acc[nf], 0, 0, 0);
            acc[nf] = __builtin_amdgcn_mfma_f32_16x16x32_bf16(al, bh, acc[nf], 0, 0, 0);
            acc[nf] = __builtin_amdgcn_mfma_f32_16x16x32_bf16(ah, bl, acc[nf], 0, 0, 0);
        }
        __syncthreads();
    }

    // ---- fused epilogue: bias, s1/s2, emb -> fp16 via LDS repack ----
    __half* hl = (__half*)lds;   // [64][144]
    #pragma unroll
    for (int r = 0; r < 4; ++r) {
        const int lrow = w * 16 + (l >> 4) * 4 + r;
        float p1 = 0.f, p2 = 0.f;
        #pragma unroll
        for (int nf = 0; nf < 8; ++nf) {
            const float e = acc[nf][r] + bias_v[nf];
            p1 += e * av1[nf];
            p2 += e * av2[nf];
            hl[lrow * 144 + nf * 16 + (l & 15)] = __float2half(e);
        }
        p1 += __shfl_xor(p1, 1); p1 += __shfl_xor(p1, 2);
        p1 += __shfl_xor(p1, 4); p1 += __shfl_xor(p1, 8);
        p2 += __shfl_xor(p2, 1); p2 += __shfl_xor(p2, 2);
        p2 += __shfl_xor(p2, 4); p2 += __shfl_xor(p2, 8);
        const int gm = gm0 + lrow;
        if ((l & 15) == 0 && gm < N) { s1[gm] = p1; s2[gm] = p2; }
    }
    __syncthreads();
    // coalesced copy LDS fp16 -> global (64 rows x 16 uint4 = 1024 uint4)
    #pragma unroll
    for (int i = 0; i < 4; ++i) {
        const int idx = i * 256 + tid;
        const int row = idx >> 4, seg = idx & 15;
        if (gm0 + row < N) {
            const uint4 u = *(const uint4*)&hl[row * 144 + seg * 8];
            ((uint4*)emb_h)[(size_t)(gm0 + row) * 16 + seg] = u;
        }
    }

    // ---- rank epilogue: coalesced writes (atomics long since drained) ----
    #pragma unroll
    for (int i = 0; i < 8; ++i) {
        if (i < ept) {
            const int e = gtid + i * T;
            if (e < E) rank[e] = rnk[i];
        }
    }
}

// ---------------------------------------------------------------------------
// rank tail (only if E exceeds the gemm grid's 8-slot capacity)
// ---------------------------------------------------------------------------
__global__ __launch_bounds__(256) void rank_tail_kernel(
    const int* __restrict__ edges, int* __restrict__ deg,
    int* __restrict__ rank, int e0base, int E)
{
    const int e = e0base + blockIdx.x * 256 + threadIdx.x;
    if (e >= E) return;
    const int2 ed = ((const int2*)edges)[e];
    rank[e] = atomicAdd(&deg[ed.x], 1);
}

__global__ __launch_bounds__(256) void scan1_kernel(
    const int* __restrict__ deg, int* __restrict__ off,
    int* __restrict__ bsum, int N)
{
    __shared__ int lds[256];
    const int t = threadIdx.x;
    const int base = blockIdx.x * 1024 + t * 4;
    int v[4];
    int ts = 0;
    #pragma unroll
    for (int j = 0; j < 4; ++j) {
        v[j] = (base + j < N) ? deg[base + j] : 0;
        ts += v[j];
    }
    lds[t] = ts;
    __syncthreads();
    for (int d = 1; d < 256; d <<= 1) {
        int xv = (t >= d) ? lds[t - d] : 0;
        __syncthreads();
        lds[t] += xv;
        __syncthreads();
    }
    int run = lds[t] - ts;
    #pragma unroll
    for (int j = 0; j < 4; ++j) {
        if (base + j < N) off[base + j] = run;
        run += v[j];
    }
    if (t == 255) bsum[blockIdx.x] = lds[255];
}

// scan3 (scan2 fused): each block computes its own bsum prefix (<=256 adds),
// finalizes offsets, detects bidx==arange (flag stays 0 if identity).
__global__ __launch_bounds__(256) void scan3_kernel(
    int* __restrict__ off, const int* __restrict__ bsum,
    const int* __restrict__ bidx, int* __restrict__ flag, int N, int E)
{
    __shared__ int red[256];
    const int t = threadIdx.x;
    const int chunk = (int)(blockIdx.x >> 2);   // block's 1024-chunk (uniform)
    int s = 0;
    for (int j = t; j < chunk; j += 256) s += bsum[j];
    red[t] = s;
    __syncthreads();
    #pragma unroll
    for (int d = 128; d > 0; d >>= 1) {
        if (t < d) red[t] += red[t + d];
        __syncthreads();
    }
    const int pref = red[0];
    const int i = blockIdx.x * 256 + t;
    if (i < N) {
        off[i] += pref;
        if (bidx[i] != i) atomicOr(flag, 1);
    }
    if (i == 0) off[N] = E;
}

// ---------------------------------------------------------------------------
// fill: no atomic — pos = precomputed rank. 4 edges/thread for ILP.
// ---------------------------------------------------------------------------
__global__ __launch_bounds__(256) void fill_kernel(
    const int* __restrict__ edges, const int* __restrict__ off,
    const int* __restrict__ rank, int* __restrict__ csr, int E)
{
    const int e0 = (blockIdx.x * 256 + threadIdx.x) * 4;
    if (e0 + 3 < E) {
        const int4 ea = ((const int4*)edges)[(e0 >> 1) + 0];
        const int4 eb = ((const int4*)edges)[(e0 >> 1) + 1];
        const int4 rk = ((const int4*)rank)[e0 >> 2];
        csr[off[ea.x] + rk.x] = ea.y;
        csr[off[ea.z] + rk.y] = ea.w;
        csr[off[eb.x] + rk.z] = eb.y;
        csr[off[eb.z] + rk.w] = eb.w;
    } else if (e0 < E) {
        for (int e = e0; e < E; ++e) {
            const int2 ed = ((const int2*)edges)[e];
            csr[off[ed.x] + rank[e]] = ed.y;
        }
    }
}

// ---------------------------------------------------------------------------
// K3: gather aggregation. Wave = 1 node.
// Phase 1 (lane-parallel, per 64-edge tile): each lane scores ONE edge and
// stashes (dst,score) in wave-private LDS; row-sum accumulates here.
// Phase 2: 4 groups x 16 col-lanes read pairs back via broadcast ds_read,
// 32 edges per iter (up to 8 row-gathers in flight per lane).
// ---------------------------------------------------------------------------
__global__ __launch_bounds__(256) void agg_kernel(
    const int* __restrict__ off, const int* __restrict__ csr,
    const float* __restrict__ s1, const float* __restrict__ s2,
    const __half* __restrict__ emb_h, const int* __restrict__ flag,
    float* __restrict__ results, float* __restrict__ out, int N)
{
    __shared__ int2 sl[4][64];   // [wave][slot] = {dst, score bits}  (2 KB)

    const int wid  = (int)((blockIdx.x * 256u + threadIdx.x) >> 6);
    const int lane = threadIdx.x & 63;
    const int wv   = threadIdx.x >> 6;
    if (wid >= N) return;
    const int eg = lane >> 4;
    const int cl = lane & 15;
    const int beg = off[wid];
    const int end = off[wid + 1];
    const float s1n = s1[wid];

    const float4* __restrict__ embrow = (const float4*)emb_h;
    int2* slot = &sl[wv][0];

    float av[8];
    #pragma unroll
    for (int k = 0; k < 8; ++k) av[k] = 0.f;
    float rsl = 0.f;

    for (int tile = beg; tile < end; tile += 64) {
        const int cnt = min(64, end - tile);           // wave-uniform
        // ---- phase 1: one edge per lane ----
        int d = 0; float sc = 0.f;
        if (lane < cnt) {
            d = csr[tile + lane];
            const float ll = s1n + s2[d];
            sc = __expf(ll > 0.f ? ll : SLOPE * ll);
        }
        rsl += sc;
        slot[lane] = make_int2(d, __float_as_int(sc));
        __builtin_amdgcn_wave_barrier();
        // ---- phase 2: grouped gather, 32 edges / iter ----
        for (int j0 = 0; j0 < cnt; j0 += 32) {
            const int nq = ((cnt - j0) + 3) >> 2;      // 1..8, wave-uniform
            int dq[8]; float scq[8];
            #pragma unroll
            for (int q = 0; q < 8; ++q) {
                dq[q] = 0; scq[q] = 0.f;
                if (q < nq) {
                    const int2 p = slot[j0 + q * 4 + eg];
                    dq[q] = p.x; scq[q] = __int_as_float(p.y);
                }
            }
            float4 vq[8];
            #pragma unroll
            for (int q = 0; q < 8; ++q)
                if (q < nq) vq[q] = embrow[(size_t)dq[q] * 16 + cl];
            #pragma unroll
            for (int q = 0; q < 8; ++q) {
                if (q < nq) {
                    const __half* hp = reinterpret_cast<const __half*>(&vq[q]);
                    #pragma unroll
                    for (int k = 0; k < 8; ++k)
                        av[k] += scq[q] * __half2float(hp[k]);
                }
            }
        }
        __builtin_amdgcn_wave_barrier();   // before next tile reuses slots
    }

    // row-sum: full 64-lane reduce of per-lane partials
    float rs = rsl;
    rs += __shfl_xor(rs, 1);  rs += __shfl_xor(rs, 2);
    rs += __shfl_xor(rs, 4);  rs += __shfl_xor(rs, 8);
    rs += __shfl_xor(rs, 16); rs += __shfl_xor(rs, 32);
    // av: reduce across the 4 edge-groups (lane bits 4,5)
    #pragma unroll
    for (int k = 0; k < 8; ++k) {
        av[k] += __shfl_xor(av[k], 16);
        av[k] += __shfl_xor(av[k], 32);
    }

    const float inv = 1.f / (rs > 0.f ? rs : 1.f);
    if (eg == 0) {
        float* dbuf = (*flag == 0) ? out : results;
        float4* rp = (float4*)&dbuf[(size_t)wid * 128 + cl * 8];
        rp[0] = make_float4(av[0] * inv, av[1] * inv, av[2] * inv, av[3] * inv);
        rp[1] = make_float4(av[4] * inv, av[5] * inv, av[6] * inv, av[7] * inv);
    }
}

// ---------------------------------------------------------------------------
// K4: out[i] = results[batch_idx[i]] — skipped when identity (agg wrote out)
// ---------------------------------------------------------------------------
__global__ __launch_bounds__(256) void gather_kernel(
    const float* __restrict__ results, const int* __restrict__ bidx,
    const int* __restrict__ flag, float* __restrict__ out, int N)
{
    if (*flag == 0) return;
    const unsigned i = blockIdx.x * 256u + threadIdx.x;
    if (i >= (unsigned)N * 32u) return;
    const unsigned n = i >> 5, c = i & 31;
    ((float4*)out)[i] = ((const float4*)results)[(size_t)bidx[n] * 32 + c];
}

extern "C" void kernel_launch(void* const* d_in, const int* in_sizes, int n_in,
                              void* d_out, int out_size, void* d_ws, size_t ws_size,
                              hipStream_t stream) {
    const float* x     = (const float*)d_in[0];
    const float* W     = (const float*)d_in[1];
    const float* b     = (const float*)d_in[2];
    const float* a     = (const float*)d_in[3];
    const int*   edges = (const int*)d_in[4];
    const int*   bidx  = (const int*)d_in[5];

    const int N = in_sizes[5];
    const int E = in_sizes[4] / 2;

    // workspace (big 16B-aligned arrays first; rank/csr aligned for int4)
    float*  results = (float*)d_ws;                          // N*128 f
    __half* emb_h   = (__half*)(results + (size_t)N * OUT_DIM); // N*128 h
    int*    rank    = (int*)(emb_h + (size_t)N * OUT_DIM);   // E
    int*    csr     = rank + E;                              // E
    float*  s1      = (float*)(csr + E);                     // N
    float*  s2      = s1 + N;                                // N
    int*    deg     = (int*)(s2 + N);                        // N
    int*    flag    = deg + N;                               // 1
    int*    off     = flag + 1;                              // N+1
    int*    bsum    = off + N + 1;                           // 256
    short*  Whi     = (short*)(bsum + 256);
    short*  Wlo     = Whi + OUT_DIM * IN_DIM;

    // zero deg[N] and flag together
    hipMemsetAsync(deg, 0, (size_t)(N + 1) * sizeof(int), stream);

    wsplit_kernel<<<(OUT_DIM * IN_DIM) / 256, 256, 0, stream>>>(W, Whi, Wlo);

    const int nGemm   = (N + 63) / 64;
    const int threads = nGemm * 256;
    int ept = (E + threads - 1) / threads;
    if (ept > 8) ept = 8;
    gemm_emb_kernel<<<nGemm, 256, 0, stream>>>(
        x, Whi, Wlo, b, a, emb_h, s1, s2, edges, deg, rank, N, E, ept);

    // tail for edges beyond the gemm grid's 8-slot capacity (rare)
    const long long cap = (long long)threads * 8;
    if ((long long)E > cap) {
        const int tailE = E - (int)cap;
        rank_tail_kernel<<<(tailE + 255) / 256, 256, 0, stream>>>(
            edges, deg, rank, (int)cap, E);
    }

    const int nb = (N + 1023) / 1024;
    scan1_kernel<<<nb, 256, 0, stream>>>(deg, off, bsum, N);
    scan3_kernel<<<(N + 255) / 256, 256, 0, stream>>>(off, bsum, bidx, flag, N, E);

    const int gE4 = (E / 4 + 255) / 256 + 1;
    fill_kernel<<<gE4, 256, 0, stream>>>(edges, off, rank, csr, E);

    const unsigned aggThreads = (unsigned)N * 64u;
    agg_kernel<<<(aggThreads + 255u) / 256u, 256, 0, stream>>>(
        off, csr, s1, s2, emb_h, flag, results, (float*)d_out, N);

    const unsigned gatherThreads = (unsigned)N * 32u;
    gather_kernel<<<(gatherThreads + 255u) / 256u, 256, 0, stream>>>(
        results, bidx, flag, (float*)d_out, N);
}

// Round 10
// 203.304 us; speedup vs baseline: 1.1298x; 1.0495x over previous
//
#include <hip/hip_runtime.h>
#include <hip/hip_fp16.h>

#define IN_DIM 256
#define OUT_DIM 128
#define SLOPE 0.1f

typedef __attribute__((ext_vector_type(8))) short short8;
typedef __attribute__((ext_vector_type(4))) float f32x4;

// round-to-nearest-even f32 -> bf16 bits
__device__ __forceinline__ unsigned bf16_rne(float f) {
    unsigned u = __float_as_uint(f);
    return (u + 0x7FFFu + ((u >> 16) & 1u)) >> 16;
}

// ---------------------------------------------------------------------------
// K0: pre-split W into bf16 hi/lo once
// ---------------------------------------------------------------------------
__global__ __launch_bounds__(256) void wsplit_kernel(
    const float* __restrict__ W, short* __restrict__ Whi, short* __restrict__ Wlo)
{
    const int i = blockIdx.x * 256 + threadIdx.x;   // 128*256 = 32768 elements
    const float v = W[i];
    const unsigned hb = bf16_rne(v);
    const float hf = __uint_as_float(hb << 16);
    Whi[i] = (short)hb;
    Wlo[i] = (short)bf16_rne(v - hf);
}

// ---------------------------------------------------------------------------
// Fused K1: blocks [0, nRank) = rank path (atomic ticketing), dispatched
// FIRST so the atomic storm starts immediately; blocks [nRank, ...) = gemm.
// Rank blocks have NO barriers — their atomic latency gates nothing (fixes
// R9: trickled atomics sat on the gemm's per-iteration vmcnt drain; fixes
// R3: trailing rank blocks were dispatched after all gemm blocks). The
// ~72us chip-wide atomic service overlaps the ~55us gemm.
// Gemm: emb = x @ W^T + b split-bf16 MFMA, 64-row tile, fused s1/s2 + fp16.
// ---------------------------------------------------------------------------
__global__ __launch_bounds__(256) void gemm_rank_kernel(
    const float* __restrict__ x, const short* __restrict__ Whi_g,
    const short* __restrict__ Wlo_g, const float* __restrict__ bias,
    const float* __restrict__ a, __half* __restrict__ emb_h,
    float* __restrict__ s1, float* __restrict__ s2,
    const int* __restrict__ edges, int* __restrict__ deg,
    int* __restrict__ rank, int N, int E, int nRank, int span)
{
    __shared__ short lds[12288];          // 24 KB (gemm path only)

    if ((int)blockIdx.x < nRank) {
        // ---------------- rank path: barrier-free atomic ticketing ----------
        const int rb   = (int)blockIdx.x;
        const int base = rb * span;
        const int endb = min(base + span, E);
        for (int e0 = base + (int)threadIdx.x * 4; e0 < endb; e0 += 1024) {
            if (e0 + 3 < endb) {
                const int4 ea = ((const int4*)edges)[(e0 >> 1) + 0];
                const int4 eb = ((const int4*)edges)[(e0 >> 1) + 1];
                const int r0 = atomicAdd(&deg[ea.x], 1);
                const int r1 = atomicAdd(&deg[ea.z], 1);
                const int r2 = atomicAdd(&deg[eb.x], 1);
                const int r3 = atomicAdd(&deg[eb.z], 1);
                ((int4*)rank)[e0 >> 2] = make_int4(r0, r1, r2, r3);
            } else {
                for (int e = e0; e < endb; ++e) {
                    const int2 ed = ((const int2*)edges)[e];
                    rank[e] = atomicAdd(&deg[ed.x], 1);
                }
            }
        }
        return;
    }

    // ---------------- gemm path ----------------
    short* Ahi = lds;                     // 64 x 32 bf16
    short* Alo = lds + 2048;
    short* Bhi = lds + 4096;              // 128 x 32 bf16
    short* Blo = lds + 8192;

    const int tid = threadIdx.x;
    const int l   = tid & 63;
    const int w   = tid >> 6;
    const int gm0 = ((int)blockIdx.x - nRank) * 64;

    // A staging: 64 rows x 4 chunks -> 1 chunk/thread
    const int arow = tid >> 2;            // 0..63
    const int akc  = tid & 3;             // 0..3
    const int gmA  = gm0 + arow;
    const bool av_ok = (gmA < N);
    // B staging: 128 rows x 4 chunks -> 2 chunks/thread
    const int brow = tid >> 1;            // 0..127
    const int bkc0 = (tid & 1) * 2;

    f32x4 acc[8];
    #pragma unroll
    for (int j = 0; j < 8; ++j) acc[j] = (f32x4)0.f;

    float bias_v[8], av1[8], av2[8];
    #pragma unroll
    for (int nf = 0; nf < 8; ++nf) {
        const int col = nf * 16 + (l & 15);
        bias_v[nf] = bias[col];
        av1[nf]    = a[col];
        av2[nf]    = a[OUT_DIM + col];
    }

    for (int ks = 0; ks < 8; ++ks) {
        const int k0 = ks * 32;
        // ---- stage A (f32 -> hi/lo split) ----
        {
            float v[8];
            if (av_ok) {
                const float4 p0 = *(const float4*)&x[(size_t)gmA * IN_DIM + k0 + akc * 8];
                const float4 p1 = *(const float4*)&x[(size_t)gmA * IN_DIM + k0 + akc * 8 + 4];
                v[0]=p0.x; v[1]=p0.y; v[2]=p0.z; v[3]=p0.w;
                v[4]=p1.x; v[5]=p1.y; v[6]=p1.z; v[7]=p1.w;
            } else {
                #pragma unroll
                for (int j = 0; j < 8; ++j) v[j] = 0.f;
            }
            short8 h8, l8;
            #pragma unroll
            for (int j = 0; j < 8; ++j) {
                unsigned hb = bf16_rne(v[j]);
                float hf = __uint_as_float(hb << 16);
                h8[j] = (short)hb;
                l8[j] = (short)bf16_rne(v[j] - hf);
            }
            *(short8*)&Ahi[akc * 512 + arow * 8] = h8;
            *(short8*)&Alo[akc * 512 + arow * 8] = l8;
        }
        // ---- stage B (pure copy of pre-split W) ----
        #pragma unroll
        for (int q = 0; q < 2; ++q) {
            const int kc = bkc0 + q;
            const short8 h8 = *(const short8*)&Whi_g[brow * IN_DIM + k0 + kc * 8];
            const short8 l8 = *(const short8*)&Wlo_g[brow * IN_DIM + k0 + kc * 8];
            *(short8*)&Bhi[kc * 1024 + brow * 8] = h8;
            *(short8*)&Blo[kc * 1024 + brow * 8] = l8;
        }
        __syncthreads();

        // ---- compute: wave w owns rows w*16..w*16+15, all 128 cols ----
        const int arow_f = w * 16 + (l & 15);
        const int aoff   = (l >> 4) * 512 + arow_f * 8;
        const short8 ah = *(const short8*)&Ahi[aoff];
        const short8 al = *(const short8*)&Alo[aoff];
        #pragma unroll
        for (int nf = 0; nf < 8; ++nf) {
            const int col = nf * 16 + (l & 15);
            const int boff = (l >> 4) * 1024 + col * 8;
            const short8 bh = *(const short8*)&Bhi[boff];
            const short8 bl = *(const short8*)&Blo[boff];
            acc[nf] = __builtin_amdgcn_mfma_f32_16x16x32_bf16(ah, bh, acc[nf], 0, 0, 0);
            acc[nf] = __builtin_amdgcn_mfma_f32_16x16x32_bf16(al, bh, acc[nf], 0, 0, 0);
            acc[nf] = __builtin_amdgcn_mfma_f32_16x16x32_bf16(ah, bl, acc[nf], 0, 0, 0);
        }
        __syncthreads();
    }

    // ---- fused epilogue: bias, s1/s2, emb -> fp16 via LDS repack ----
    __half* hl = (__half*)lds;   // [64][144]
    #pragma unroll
    for (int r = 0; r < 4; ++r) {
        const int lrow = w * 16 + (l >> 4) * 4 + r;
        float p1 = 0.f, p2 = 0.f;
        #pragma unroll
        for (int nf = 0; nf < 8; ++nf) {
            const float e = acc[nf][r] + bias_v[nf];
            p1 += e * av1[nf];
            p2 += e * av2[nf];
            hl[lrow * 144 + nf * 16 + (l & 15)] = __float2half(e);
        }
        p1 += __shfl_xor(p1, 1); p1 += __shfl_xor(p1, 2);
        p1 += __shfl_xor(p1, 4); p1 += __shfl_xor(p1, 8);
        p2 += __shfl_xor(p2, 1); p2 += __shfl_xor(p2, 2);
        p2 += __shfl_xor(p2, 4); p2 += __shfl_xor(p2, 8);
        const int gm = gm0 + lrow;
        if ((l & 15) == 0 && gm < N) { s1[gm] = p1; s2[gm] = p2; }
    }
    __syncthreads();
    // coalesced copy LDS fp16 -> global (64 rows x 16 uint4 = 1024 uint4)
    #pragma unroll
    for (int i = 0; i < 4; ++i) {
        const int idx = i * 256 + tid;
        const int row = idx >> 4, seg = idx & 15;
        if (gm0 + row < N) {
            const uint4 u = *(const uint4*)&hl[row * 144 + seg * 8];
            ((uint4*)emb_h)[(size_t)(gm0 + row) * 16 + seg] = u;
        }
    }
}

__global__ __launch_bounds__(256) void scan1_kernel(
    const int* __restrict__ deg, int* __restrict__ off,
    int* __restrict__ bsum, int N)
{
    __shared__ int lds[256];
    const int t = threadIdx.x;
    const int base = blockIdx.x * 1024 + t * 4;
    int v[4];
    int ts = 0;
    #pragma unroll
    for (int j = 0; j < 4; ++j) {
        v[j] = (base + j < N) ? deg[base + j] : 0;
        ts += v[j];
    }
    lds[t] = ts;
    __syncthreads();
    for (int d = 1; d < 256; d <<= 1) {
        int xv = (t >= d) ? lds[t - d] : 0;
        __syncthreads();
        lds[t] += xv;
        __syncthreads();
    }
    int run = lds[t] - ts;
    #pragma unroll
    for (int j = 0; j < 4; ++j) {
        if (base + j < N) off[base + j] = run;
        run += v[j];
    }
    if (t == 255) bsum[blockIdx.x] = lds[255];
}

// scan3 (scan2 fused): each block computes its own bsum prefix (<=256 adds),
// finalizes offsets, detects bidx==arange (flag stays 0 if identity).
__global__ __launch_bounds__(256) void scan3_kernel(
    int* __restrict__ off, const int* __restrict__ bsum,
    const int* __restrict__ bidx, int* __restrict__ flag, int N, int E)
{
    __shared__ int red[256];
    const int t = threadIdx.x;
    const int chunk = (int)(blockIdx.x >> 2);   // block's 1024-chunk (uniform)
    int s = 0;
    for (int j = t; j < chunk; j += 256) s += bsum[j];
    red[t] = s;
    __syncthreads();
    #pragma unroll
    for (int d = 128; d > 0; d >>= 1) {
        if (t < d) red[t] += red[t + d];
        __syncthreads();
    }
    const int pref = red[0];
    const int i = blockIdx.x * 256 + t;
    if (i < N) {
        off[i] += pref;
        if (bidx[i] != i) atomicOr(flag, 1);
    }
    if (i == 0) off[N] = E;
}

// ---------------------------------------------------------------------------
// fill: no atomic — pos = precomputed rank. 4 edges/thread for ILP.
// ---------------------------------------------------------------------------
__global__ __launch_bounds__(256) void fill_kernel(
    const int* __restrict__ edges, const int* __restrict__ off,
    const int* __restrict__ rank, int* __restrict__ csr, int E)
{
    const int e0 = (blockIdx.x * 256 + threadIdx.x) * 4;
    if (e0 + 3 < E) {
        const int4 ea = ((const int4*)edges)[(e0 >> 1) + 0];
        const int4 eb = ((const int4*)edges)[(e0 >> 1) + 1];
        const int4 rk = ((const int4*)rank)[e0 >> 2];
        csr[off[ea.x] + rk.x] = ea.y;
        csr[off[ea.z] + rk.y] = ea.w;
        csr[off[eb.x] + rk.z] = eb.y;
        csr[off[eb.z] + rk.w] = eb.w;
    } else if (e0 < E) {
        for (int e = e0; e < E; ++e) {
            const int2 ed = ((const int2*)edges)[e];
            csr[off[ed.x] + rank[e]] = ed.y;
        }
    }
}

// ---------------------------------------------------------------------------
// K3: gather aggregation. Wave = 1 node.
// Phase 1 (lane-parallel, per 64-edge tile): each lane scores ONE edge and
// stashes (dst,score) in wave-private LDS; row-sum accumulates here.
// Phase 2: 4 groups x 16 col-lanes read pairs back via broadcast ds_read,
// 32 edges per iter (up to 8 row-gathers in flight per lane).
// ---------------------------------------------------------------------------
__global__ __launch_bounds__(256) void agg_kernel(
    const int* __restrict__ off, const int* __restrict__ csr,
    const float* __restrict__ s1, const float* __restrict__ s2,
    const __half* __restrict__ emb_h, const int* __restrict__ flag,
    float* __restrict__ results, float* __restrict__ out, int N)
{
    __shared__ int2 sl[4][64];   // [wave][slot] = {dst, score bits}  (2 KB)

    const int wid  = (int)((blockIdx.x * 256u + threadIdx.x) >> 6);
    const int lane = threadIdx.x & 63;
    const int wv   = threadIdx.x >> 6;
    if (wid >= N) return;
    const int eg = lane >> 4;
    const int cl = lane & 15;
    const int beg = off[wid];
    const int end = off[wid + 1];
    const float s1n = s1[wid];

    const float4* __restrict__ embrow = (const float4*)emb_h;
    int2* slot = &sl[wv][0];

    float av[8];
    #pragma unroll
    for (int k = 0; k < 8; ++k) av[k] = 0.f;
    float rsl = 0.f;

    for (int tile = beg; tile < end; tile += 64) {
        const int cnt = min(64, end - tile);           // wave-uniform
        // ---- phase 1: one edge per lane ----
        int d = 0; float sc = 0.f;
        if (lane < cnt) {
            d = csr[tile + lane];
            const float ll = s1n + s2[d];
            sc = __expf(ll > 0.f ? ll : SLOPE * ll);
        }
        rsl += sc;
        slot[lane] = make_int2(d, __float_as_int(sc));
        __builtin_amdgcn_wave_barrier();
        // ---- phase 2: grouped gather, 32 edges / iter ----
        for (int j0 = 0; j0 < cnt; j0 += 32) {
            const int nq = ((cnt - j0) + 3) >> 2;      // 1..8, wave-uniform
            int dq[8]; float scq[8];
            #pragma unroll
            for (int q = 0; q < 8; ++q) {
                dq[q] = 0; scq[q] = 0.f;
                if (q < nq) {
                    const int2 p = slot[j0 + q * 4 + eg];
                    dq[q] = p.x; scq[q] = __int_as_float(p.y);
                }
            }
            float4 vq[8];
            #pragma unroll
            for (int q = 0; q < 8; ++q)
                if (q < nq) vq[q] = embrow[(size_t)dq[q] * 16 + cl];
            #pragma unroll
            for (int q = 0; q < 8; ++q) {
                if (q < nq) {
                    const __half* hp = reinterpret_cast<const __half*>(&vq[q]);
                    #pragma unroll
                    for (int k = 0; k < 8; ++k)
                        av[k] += scq[q] * __half2float(hp[k]);
                }
            }
        }
        __builtin_amdgcn_wave_barrier();   // before next tile reuses slots
    }

    // row-sum: full 64-lane reduce of per-lane partials
    float rs = rsl;
    rs += __shfl_xor(rs, 1);  rs += __shfl_xor(rs, 2);
    rs += __shfl_xor(rs, 4);  rs += __shfl_xor(rs, 8);
    rs += __shfl_xor(rs, 16); rs += __shfl_xor(rs, 32);
    // av: reduce across the 4 edge-groups (lane bits 4,5)
    #pragma unroll
    for (int k = 0; k < 8; ++k) {
        av[k] += __shfl_xor(av[k], 16);
        av[k] += __shfl_xor(av[k], 32);
    }

    const float inv = 1.f / (rs > 0.f ? rs : 1.f);
    if (eg == 0) {
        float* dbuf = (*flag == 0) ? out : results;
        float4* rp = (float4*)&dbuf[(size_t)wid * 128 + cl * 8];
        rp[0] = make_float4(av[0] * inv, av[1] * inv, av[2] * inv, av[3] * inv);
        rp[1] = make_float4(av[4] * inv, av[5] * inv, av[6] * inv, av[7] * inv);
    }
}

// ---------------------------------------------------------------------------
// K4: out[i] = results[batch_idx[i]] — skipped when identity (agg wrote out)
// ---------------------------------------------------------------------------
__global__ __launch_bounds__(256) void gather_kernel(
    const float* __restrict__ results, const int* __restrict__ bidx,
    const int* __restrict__ flag, float* __restrict__ out, int N)
{
    if (*flag == 0) return;
    const unsigned i = blockIdx.x * 256u + threadIdx.x;
    if (i >= (unsigned)N * 32u) return;
    const unsigned n = i >> 5, c = i & 31;
    ((float4*)out)[i] = ((const float4*)results)[(size_t)bidx[n] * 32 + c];
}

extern "C" void kernel_launch(void* const* d_in, const int* in_sizes, int n_in,
                              void* d_out, int out_size, void* d_ws, size_t ws_size,
                              hipStream_t stream) {
    const float* x     = (const float*)d_in[0];
    const float* W     = (const float*)d_in[1];
    const float* b     = (const float*)d_in[2];
    const float* a     = (const float*)d_in[3];
    const int*   edges = (const int*)d_in[4];
    const int*   bidx  = (const int*)d_in[5];

    const int N = in_sizes[5];
    const int E = in_sizes[4] / 2;

    // workspace (big 16B-aligned arrays first; rank/csr aligned for int4)
    float*  results = (float*)d_ws;                          // N*128 f
    __half* emb_h   = (__half*)(results + (size_t)N * OUT_DIM); // N*128 h
    int*    rank    = (int*)(emb_h + (size_t)N * OUT_DIM);   // E
    int*    csr     = rank + E;                              // E
    float*  s1      = (float*)(csr + E);                     // N
    float*  s2      = s1 + N;                                // N
    int*    deg     = (int*)(s2 + N);                        // N
    int*    flag    = deg + N;                               // 1
    int*    off     = flag + 1;                              // N+1
    int*    bsum    = off + N + 1;                           // 256
    short*  Whi     = (short*)(bsum + 256);
    short*  Wlo     = Whi + OUT_DIM * IN_DIM;

    // zero deg[N] and flag together
    hipMemsetAsync(deg, 0, (size_t)(N + 1) * sizeof(int), stream);

    wsplit_kernel<<<(OUT_DIM * IN_DIM) / 256, 256, 0, stream>>>(W, Whi, Wlo);

    const int nRank = 64;
    const int span  = (((E + nRank - 1) / nRank) + 3) & ~3;   // per-block edges, /4
    const int nGemm = (N + 63) / 64;
    gemm_rank_kernel<<<nRank + nGemm, 256, 0, stream>>>(
        x, Whi, Wlo, b, a, emb_h, s1, s2, edges, deg, rank, N, E, nRank, span);

    const int nb = (N + 1023) / 1024;
    scan1_kernel<<<nb, 256, 0, stream>>>(deg, off, bsum, N);
    scan3_kernel<<<(N + 255) / 256, 256, 0, stream>>>(off, bsum, bidx, flag, N, E);

    const int gE4 = (E / 4 + 255) / 256 + 1;
    fill_kernel<<<gE4, 256, 0, stream>>>(edges, off, rank, csr, E);

    const unsigned aggThreads = (unsigned)N * 64u;
    agg_kernel<<<(aggThreads + 255u) / 256u, 256, 0, stream>>>(
        off, csr, s1, s2, emb_h, flag, results, (float*)d_out, N);

    const unsigned gatherThreads = (unsigned)N * 32u;
    gather_kernel<<<(gatherThreads + 255u) / 256u, 256, 0, stream>>>(
        results, bidx, flag, (float*)d_out, N);
}